// Round 6
// baseline (547.116 us; speedup 1.0000x reference)
//
#include <hip/hip_runtime.h>
#include <hip/hip_bf16.h>
#include <math.h>

#define NRES 512
#define CS 384
#define CZ 128
#define NH 12
#define PQ 4
#define PV 8
#define OUT_DIM 2112   // H*(C + 3*PV + PV + CZ)
#define PRJ 1152       // packed projection width: q192|k192|v192|qp144|kp144|vp288

typedef __attribute__((ext_vector_type(8))) short short8;
typedef __attribute__((ext_vector_type(4))) float f32x4;

__device__ __forceinline__ float softplusf(float x) { return log1pf(expf(x)); }

__device__ __forceinline__ unsigned short f2bf(float f) {
    union { float f; unsigned u; } v; v.f = f;
    unsigned r = v.u + 0x7FFF + ((v.u >> 16) & 1);
    return (unsigned short)(r >> 16);
}

__device__ __forceinline__ float bf2f(unsigned u) {
    union { unsigned u; float f; } v; v.u = u << 16;
    return v.f;
}

// ---------------------------------------------------------------------------
// Pack 6 projection weight matrices into Bp[384][1152]
// ---------------------------------------------------------------------------
__global__ void pack_proj_kernel(const float* __restrict__ Wq, const float* __restrict__ Wk,
                                 const float* __restrict__ Wv, const float* __restrict__ Wqp,
                                 const float* __restrict__ Wkp, const float* __restrict__ Wvp,
                                 float* __restrict__ Bp)
{
    int x = blockIdx.x * blockDim.x + threadIdx.x;
    if (x >= CS * PRJ) return;
    int k = x / PRJ, c = x % PRJ;
    float v;
    if      (c < 192)  v = Wq [k * 192 + c];
    else if (c < 384)  v = Wk [k * 192 + (c - 192)];
    else if (c < 576)  v = Wv [k * 192 + (c - 384)];
    else if (c < 720)  v = Wqp[k * 144 + (c - 576)];
    else if (c < 864)  v = Wkp[k * 144 + (c - 720)];
    else               v = Wvp[k * 288 + (c - 864)];
    Bp[x] = v;
}

// ---------------------------------------------------------------------------
// Tiled f32 GEMM: BM=64, BN=64, BK=16, 256 threads, 4x4 micro-tile.
// If gridDim.z > 1: k-split partial, atomicAdd into pre-initialized C.
// ---------------------------------------------------------------------------
__global__ void gemm_tiled(const float* __restrict__ A, const float* __restrict__ B,
                           const float* __restrict__ bias, const float* __restrict__ res,
                           float* __restrict__ C, int M, int K, int Nc, int relu, int KS)
{
    __shared__ float As[16][68];
    __shared__ float Bs[16][64];
    int m0 = blockIdx.x * 64, n0 = blockIdx.y * 64;
    int kbeg = blockIdx.z * KS;
    int t = threadIdx.x;
    int tm = t >> 4, tn = t & 15;
    int lr = t >> 2, lc4 = t & 3;
    int br = t >> 4, bc4 = t & 15;
    float acc[4][4] = {{0.f}};

    for (int kt = kbeg; kt < kbeg + KS; kt += 16) {
        float4 a4 = *(const float4*)&A[(size_t)(m0 + lr) * K + kt + lc4 * 4];
        float4 b4 = *(const float4*)&B[(size_t)(kt + br) * Nc + n0 + bc4 * 4];
        As[lc4 * 4 + 0][lr] = a4.x;
        As[lc4 * 4 + 1][lr] = a4.y;
        As[lc4 * 4 + 2][lr] = a4.z;
        As[lc4 * 4 + 3][lr] = a4.w;
        *(float4*)&Bs[br][bc4 * 4] = b4;
        __syncthreads();
#pragma unroll
        for (int k = 0; k < 16; ++k) {
            float4 av = *(const float4*)&As[k][tm * 4];
            float4 bv = *(const float4*)&Bs[k][tn * 4];
            acc[0][0] = fmaf(av.x, bv.x, acc[0][0]); acc[0][1] = fmaf(av.x, bv.y, acc[0][1]);
            acc[0][2] = fmaf(av.x, bv.z, acc[0][2]); acc[0][3] = fmaf(av.x, bv.w, acc[0][3]);
            acc[1][0] = fmaf(av.y, bv.x, acc[1][0]); acc[1][1] = fmaf(av.y, bv.y, acc[1][1]);
            acc[1][2] = fmaf(av.y, bv.z, acc[1][2]); acc[1][3] = fmaf(av.y, bv.w, acc[1][3]);
            acc[2][0] = fmaf(av.z, bv.x, acc[2][0]); acc[2][1] = fmaf(av.z, bv.y, acc[2][1]);
            acc[2][2] = fmaf(av.z, bv.z, acc[2][2]); acc[2][3] = fmaf(av.z, bv.w, acc[2][3]);
            acc[3][0] = fmaf(av.w, bv.x, acc[3][0]); acc[3][1] = fmaf(av.w, bv.y, acc[3][1]);
            acc[3][2] = fmaf(av.w, bv.z, acc[3][2]); acc[3][3] = fmaf(av.w, bv.w, acc[3][3]);
        }
        __syncthreads();
    }

    if (gridDim.z > 1) {
#pragma unroll
        for (int r = 0; r < 4; ++r)
#pragma unroll
            for (int c = 0; c < 4; ++c)
                atomicAdd(&C[(size_t)(m0 + tm * 4 + r) * Nc + n0 + tn * 4 + c], acc[r][c]);
    } else {
#pragma unroll
        for (int r = 0; r < 4; ++r) {
            int row = m0 + tm * 4 + r;
            float4 v;
            float* vp = (float*)&v;
#pragma unroll
            for (int c = 0; c < 4; ++c) {
                int col = n0 + tn * 4 + c;
                float x = acc[r][c];
                if (bias) x += bias[col];
                if (res)  x += res[(size_t)row * Nc + col];
                if (relu) x = fmaxf(x, 0.f);
                vp[c] = x;
            }
            *(float4*)&C[(size_t)row * Nc + n0 + tn * 4] = v;
        }
    }
}

// ---------------------------------------------------------------------------
__global__ void init_out1_kernel(const float* __restrict__ bo, const float* __restrict__ single,
                                 float* __restrict__ out1)
{
    int x = blockIdx.x * blockDim.x + threadIdx.x;
    if (x >= NRES * CS) return;
    out1[x] = bo[x % CS] + single[x];
}

// ---------------------------------------------------------------------------
// Frames: one thread per (n, h). Writes gq (n-major), gv (n-major), sqq,
// and j-major transposed kT[h][c][j], gkT[h][x][j], sqkT[h][j].
// ---------------------------------------------------------------------------
__global__ void frames_kernel(const float* __restrict__ proj, const float* __restrict__ rot,
                              const float* __restrict__ trans,
                              float* __restrict__ gq, float* __restrict__ gv,
                              float* __restrict__ sqq,
                              float* __restrict__ kT, float* __restrict__ gkT,
                              float* __restrict__ sqkT)
{
    int x = blockIdx.x * blockDim.x + threadIdx.x;
    if (x >= NRES * NH) return;
    int n = x / NH, h = x % NH;
    float R[9], t3[3];
#pragma unroll
    for (int r = 0; r < 9; ++r) R[r] = rot[n * 9 + r];
#pragma unroll
    for (int r = 0; r < 3; ++r) t3[r] = trans[n * 3 + r];
    const float* qp = proj + (size_t)n * PRJ + 576 + h * (PQ * 3);
    const float* kp = proj + (size_t)n * PRJ + 720 + h * (PQ * 3);
    const float* vp = proj + (size_t)n * PRJ + 864 + h * (PV * 3);
    const float* kk = proj + (size_t)n * PRJ + 192 + h * 16;

#pragma unroll
    for (int c = 0; c < 16; ++c) kT[(h * 16 + c) * NRES + n] = kk[c];

    float sq = 0.f, sk = 0.f;
#pragma unroll
    for (int p = 0; p < PQ; ++p) {
        const float* in = qp + p * 3;
        float* og = gq + (size_t)n * 144 + h * (PQ * 3) + p * 3;
#pragma unroll
        for (int a = 0; a < 3; ++a) {
            float g = R[a*3+0]*in[0] + R[a*3+1]*in[1] + R[a*3+2]*in[2] + t3[a];
            og[a] = g; sq += g * g;
        }
        const float* in2 = kp + p * 3;
#pragma unroll
        for (int a = 0; a < 3; ++a) {
            float g = R[a*3+0]*in2[0] + R[a*3+1]*in2[1] + R[a*3+2]*in2[2] + t3[a];
            gkT[(h * 12 + p * 3 + a) * NRES + n] = g;
            sk += g * g;
        }
    }
    sqq[n * NH + h] = sq;
    sqkT[h * NRES + n] = sk;
#pragma unroll
    for (int p = 0; p < PV; ++p) {
        const float* in = vp + p * 3;
        float* og = gv + (size_t)n * 288 + h * (PV * 3) + p * 3;
#pragma unroll
        for (int a = 0; a < 3; ++a)
            og[a] = R[a*3+0]*in[0] + R[a*3+1]*in[1] + R[a*3+2]*in[2] + t3[a];
    }
}

// ---------------------------------------------------------------------------
// Fused IPA attention: block per i (512 threads, 8 waves), online softmax.
// Per 64-j tile: stage pair->bf16 LDS, MFMA bias, qk/cross/d2, online m/s
// update, accumulate o_pair (LDS tile) + o_v/o_pt (global v/gv). Writes
// concat row [o_v | local | norms | o_pair].
// ---------------------------------------------------------------------------
__global__ __launch_bounds__(512) void ipa_fused_kernel(
        const float* __restrict__ pair, const float* __restrict__ proj,
        const float* __restrict__ gq, const float* __restrict__ gvp,
        const float* __restrict__ kT, const float* __restrict__ gkT,
        const float* __restrict__ sqq, const float* __restrict__ sqkT,
        const float* __restrict__ Wb, const float* __restrict__ gamma_raw,
        const float* __restrict__ rot, const float* __restrict__ trans,
        float* __restrict__ concat)
{
    __shared__ unsigned short pl[64 * 128];   // bf16 swizzled pair tile (16 KB)
    __shared__ float ell[64 * 13];            // logits / e-weights tile
    __shared__ float qi[192], gqi[144], sqi[12], gam[12];
    __shared__ float mrun[12], srun[12], ffac[12];
    __shared__ float opt[288];

    int i = blockIdx.x, t = threadIdx.x;
    int lane = t & 63, w = t >> 6;

    // --- Wb B-fragments (built once) ---
    short8 bfrag[4];
    {
        int col = lane & 15;
        int kb = (lane >> 4) * 8;
#pragma unroll
        for (int ks = 0; ks < 4; ++ks) {
            short8 f;
#pragma unroll
            for (int e = 0; e < 8; ++e) {
                float v = (col < NH) ? Wb[(ks * 32 + kb + e) * NH + col] : 0.f;
                f[e] = (short)f2bf(v);
            }
            bfrag[ks] = f;
        }
    }

    for (int x = t; x < 192; x += 512) qi[x] = proj[(size_t)i * PRJ + x];
    for (int x = t; x < 144; x += 512) gqi[x] = gq[(size_t)i * 144 + x];
    if (t < 12) {
        sqi[t] = sqq[i * 12 + t];
        gam[t] = softplusf(gamma_raw[t]);
        mrun[t] = -1e30f; srun[t] = 0.f; ffac[t] = 0.f;
    }

    // accumulators
    f32x4 accp = {0.f, 0.f, 0.f, 0.f};       // t<384: o_pair (h = t>>5, zq = t&31)
    float acc2_0 = 0.f, acc2_1 = 0.f, acc2_2 = 0.f, acc2_3 = 0.f;  // t>=384: o_v/o_pt
    int xv = t - 384;
    int h0 = 0, h1 = 0, h2 = 0, h3 = 0;
    const float* pb0 = proj; const float* pb1 = proj; const float* pb2 = proj; const float* pb3 = proj;
    int st0 = 0, st1 = 0, st2 = 0, st3 = 0;
    int v3 = 0;
    if (t >= 384) {
        int idx;
        idx = xv;        if (idx < 192) { h0 = idx >> 4; pb0 = proj + 384 + idx; st0 = PRJ; }
                         else           { h0 = (idx - 192) / 24; pb0 = gvp + (idx - 192); st0 = 288; }
        idx = xv + 128;  if (idx < 192) { h1 = idx >> 4; pb1 = proj + 384 + idx; st1 = PRJ; }
                         else           { h1 = (idx - 192) / 24; pb1 = gvp + (idx - 192); st1 = 288; }
        idx = xv + 256;  { h2 = (idx - 192) / 24; pb2 = gvp + (idx - 192); st2 = 288; }
        idx = xv + 384;  if (idx < 480) { h3 = (idx - 192) / 24; pb3 = gvp + (idx - 192); st3 = 288; v3 = 1; }
    }

    const float WLc = 0.57735026918962576f;   // sqrt(1/3)
    const float WCc = 0.23570226039551584f;   // sqrt(2/(9*4))

    for (int jt = 0; jt < 8; ++jt) {
        __syncthreads();   // pl/ell free from previous tile
        // --- stage pair tile -> bf16 swizzled LDS ---
        {
            int row = t >> 3, c0 = (t & 7) * 16;
            const float* pr = pair + ((size_t)i * NRES + jt * 64 + row) * CZ + c0;
#pragma unroll
            for (int k = 0; k < 4; ++k) {
                float4 v = *(const float4*)(pr + k * 4);
                unsigned b01 = (unsigned)f2bf(v.x) | ((unsigned)f2bf(v.y) << 16);
                unsigned b23 = (unsigned)f2bf(v.z) | ((unsigned)f2bf(v.w) << 16);
                int byte = row * 256 + (((c0 + k * 4) * 2) ^ ((row & 7) << 4));
                *(uint2*)((char*)pl + byte) = make_uint2(b01, b23);
            }
        }
        __syncthreads();
        // --- MFMA bias (waves 0..3) -> ell ---
        if (w < 4) {
            f32x4 acc = {0.f, 0.f, 0.f, 0.f};
            int arow = w * 16 + (lane & 15);
            int kb2 = (lane >> 4) * 16;
#pragma unroll
            for (int ks = 0; ks < 4; ++ks) {
                int byte = arow * 256 + (((ks * 64) + kb2) ^ ((arow & 7) << 4));
                short8 afrag = *(const short8*)((const char*)pl + byte);
                acc = __builtin_amdgcn_mfma_f32_16x16x32_bf16(afrag, bfrag[ks], acc, 0, 0, 0);
            }
            int crow = w * 16 + (lane >> 4) * 4;
            int ccol = lane & 15;
            if (ccol < NH) {
#pragma unroll
                for (int r = 0; r < 4; ++r) ell[(crow + r) * 13 + ccol] = acc[r];
            }
        }
        __syncthreads();
        // --- qk / cross / d2 -> final logits in ell ---
        {
            int jl = t & 63;
            int j = jt * 64 + jl;
#pragma unroll
            for (int rep = 0; rep < 2; ++rep) {
                int h = (t >> 6) + rep * 8;
                if (h < NH) {
                    float qk = 0.f;
#pragma unroll
                    for (int c = 0; c < 16; ++c)
                        qk = fmaf(qi[h * 16 + c], kT[(h * 16 + c) * NRES + j], qk);
                    float cross = 0.f;
#pragma unroll
                    for (int x = 0; x < 12; ++x)
                        cross = fmaf(gqi[h * 12 + x], gkT[(h * 12 + x) * NRES + j], cross);
                    float d2 = sqi[h] + sqkT[h * NRES + j] - 2.f * cross;
                    ell[jl * 13 + h] = WLc * (qk * 0.25f + ell[jl * 13 + h]
                                              - 0.5f * WCc * gam[h] * d2);
                }
            }
        }
        __syncthreads();
        // --- online max update (t<12) ---
        if (t < NH) {
            float tm = -1e30f;
            for (int jl = 0; jl < 64; ++jl) tm = fmaxf(tm, ell[jl * 13 + t]);
            float mo = mrun[t];
            float mn = fmaxf(mo, tm);
            float f = expf(mo - mn);
            mrun[t] = mn; ffac[t] = f; srun[t] *= f;
        }
        __syncthreads();
        // --- e = exp(l - m) ---
        {
            int jl = t & 63;
#pragma unroll
            for (int rep = 0; rep < 2; ++rep) {
                int h = (t >> 6) + rep * 8;
                if (h < NH) ell[jl * 13 + h] = expf(ell[jl * 13 + h] - mrun[h]);
            }
        }
        __syncthreads();
        // --- srun += tile sum (wave0 lanes <12; serial, no extra barrier) ---
        if (t < NH) {
            float s = 0.f;
            for (int jl = 0; jl < 64; ++jl) s += ell[jl * 13 + t];
            srun[t] += s;
        }
        // --- accumulation ---
        if (t < 384) {
            int h = t >> 5, zq = t & 31;
            float f = ffac[h];
            accp.x *= f; accp.y *= f; accp.z *= f; accp.w *= f;
            for (int jl = 0; jl < 64; ++jl) {
                float ev = ell[jl * 13 + h];
                int byte = jl * 256 + ((zq * 8) ^ ((jl & 7) << 4));
                uint2 pv = *(const uint2*)((const char*)pl + byte);
                accp.x = fmaf(ev, bf2f(pv.x & 0xffffu), accp.x);
                accp.y = fmaf(ev, bf2f(pv.x >> 16), accp.y);
                accp.z = fmaf(ev, bf2f(pv.y & 0xffffu), accp.z);
                accp.w = fmaf(ev, bf2f(pv.y >> 16), accp.w);
            }
        } else {
            acc2_0 *= ffac[h0]; acc2_1 *= ffac[h1]; acc2_2 *= ffac[h2];
            if (v3) acc2_3 *= ffac[h3];
            const float* p0 = pb0 + (size_t)(jt * 64) * st0;
            const float* p1 = pb1 + (size_t)(jt * 64) * st1;
            const float* p2 = pb2 + (size_t)(jt * 64) * st2;
            const float* p3 = pb3 + (size_t)(jt * 64) * st3;
            for (int jl = 0; jl < 64; ++jl) {
                acc2_0 = fmaf(ell[jl * 13 + h0], *p0, acc2_0); p0 += st0;
                acc2_1 = fmaf(ell[jl * 13 + h1], *p1, acc2_1); p1 += st1;
                acc2_2 = fmaf(ell[jl * 13 + h2], *p2, acc2_2); p2 += st2;
                if (v3) { acc2_3 = fmaf(ell[jl * 13 + h3], *p3, acc2_3); p3 += st3; }
            }
        }
    }
    __syncthreads();
    // --- finalize ---
    if (t < 384) {
        int h = t >> 5, zq = t & 31;
        float inv = 1.f / srun[h];
        float4 o;
        o.x = accp.x * inv; o.y = accp.y * inv; o.z = accp.z * inv; o.w = accp.w * inv;
        *(float4*)&concat[(size_t)i * OUT_DIM + 576 + h * 128 + zq * 4] = o;
    } else {
        int idx;
        idx = xv;       { float v = acc2_0 / srun[h0];
                          if (idx < 192) concat[(size_t)i * OUT_DIM + idx] = v; else opt[idx - 192] = v; }
        idx = xv + 128; { float v = acc2_1 / srun[h1];
                          if (idx < 192) concat[(size_t)i * OUT_DIM + idx] = v; else opt[idx - 192] = v; }
        idx = xv + 256; { opt[idx - 192] = acc2_2 / srun[h2]; }
        idx = xv + 384; if (v3) { opt[idx - 192] = acc2_3 / srun[h3]; }
    }
    __syncthreads();
    if (t < 96) {
        int h = t >> 3, p = t & 7;
        float b0 = opt[h * 24 + p * 3 + 0] - trans[i * 3 + 0];
        float b1 = opt[h * 24 + p * 3 + 1] - trans[i * 3 + 1];
        float b2 = opt[h * 24 + p * 3 + 2] - trans[i * 3 + 2];
        const float* Ri = rot + i * 9;
        float l0 = Ri[0] * b0 + Ri[3] * b1 + Ri[6] * b2;
        float l1 = Ri[1] * b0 + Ri[4] * b1 + Ri[7] * b2;
        float l2 = Ri[2] * b0 + Ri[5] * b1 + Ri[8] * b2;
        float* c = concat + (size_t)i * OUT_DIM;
        c[192 + h * 24 + p * 3 + 0] = l0;
        c[192 + h * 24 + p * 3 + 1] = l1;
        c[192 + h * 24 + p * 3 + 2] = l2;
        c[480 + h * 8 + p] = sqrtf(l0 * l0 + l1 * l1 + l2 * l2 + 1e-8f);
    }
}

// ---------------------------------------------------------------------------
// LayerNorm over 384
// ---------------------------------------------------------------------------
__global__ void ln_kernel(const float* __restrict__ x, const float* __restrict__ g,
                          const float* __restrict__ b, float* __restrict__ y)
{
    int i = blockIdx.x, t = threadIdx.x;
    const float* xr = x + (size_t)i * CS;
    float a0 = xr[t], a1 = xr[t + 128], a2 = xr[t + 256];
    __shared__ float red[128];
    red[t] = a0 + a1 + a2;
    __syncthreads();
    for (int s = 64; s > 0; s >>= 1) { if (t < s) red[t] += red[t + s]; __syncthreads(); }
    float mean = red[0] * (1.f / CS);
    __syncthreads();
    float d0 = a0 - mean, d1 = a1 - mean, d2 = a2 - mean;
    red[t] = d0 * d0 + d1 * d1 + d2 * d2;
    __syncthreads();
    for (int s = 64; s > 0; s >>= 1) { if (t < s) red[t] += red[t + s]; __syncthreads(); }
    float rstd = rsqrtf(red[0] * (1.f / CS) + 1e-5f);
    float* yr = y + (size_t)i * CS;
    yr[t]       = d0 * rstd * g[t]       + b[t];
    yr[t + 128] = d1 * rstd * g[t + 128] + b[t + 128];
    yr[t + 256] = d2 * rstd * g[t + 256] + b[t + 256];
}

// ---------------------------------------------------------------------------
// Backbone: one block (128 thr) per residue; LDS reduce over 6 comps.
// ---------------------------------------------------------------------------
__global__ void backbone_kernel(const float* __restrict__ sfin, const float* __restrict__ Wbu,
                                const float* __restrict__ bbu, const float* __restrict__ rot,
                                const float* __restrict__ trans, float* __restrict__ rot_out,
                                float* __restrict__ trans_out)
{
    int i = blockIdx.x, t = threadIdx.x;
    float part[6] = {0.f, 0.f, 0.f, 0.f, 0.f, 0.f};
    for (int k = t; k < CS; k += 128) {
        float s = sfin[(size_t)i * CS + k];
        const float* wr = Wbu + k * 6;
#pragma unroll
        for (int c = 0; c < 6; ++c) part[c] = fmaf(s, wr[c], part[c]);
    }
    __shared__ float red[6][128];
#pragma unroll
    for (int c = 0; c < 6; ++c) red[c][t] = part[c];
    __syncthreads();
    for (int s = 64; s > 0; s >>= 1) {
        if (t < s) {
#pragma unroll
            for (int c = 0; c < 6; ++c) red[c][t] += red[c][t + s];
        }
        __syncthreads();
    }
    if (t == 0) {
        float u[6];
#pragma unroll
        for (int c = 0; c < 6; ++c) u[c] = red[c][0] + bbu[c];
        float a = 1.f, b = u[0], c2 = u[1], d = u[2];
        float inv = rsqrtf(a * a + b * b + c2 * c2 + d * d);
        a *= inv; b *= inv; c2 *= inv; d *= inv;
        float R[9] = { a*a + b*b - c2*c2 - d*d, 2.f*(b*c2 - a*d),        2.f*(b*d + a*c2),
                       2.f*(b*c2 + a*d),        a*a - b*b + c2*c2 - d*d, 2.f*(c2*d - a*b),
                       2.f*(b*d - a*c2),        2.f*(c2*d + a*b),        a*a - b*b - c2*c2 + d*d };
        const float* Ri = rot + i * 9;
        float Rn[9];
#pragma unroll
        for (int r = 0; r < 3; ++r)
#pragma unroll
            for (int cc = 0; cc < 3; ++cc) {
                float s2 = 0.f;
#pragma unroll
                for (int kk = 0; kk < 3; ++kk) s2 += Ri[r * 3 + kk] * R[kk * 3 + cc];
                Rn[r * 3 + cc] = s2;
            }
#pragma unroll
        for (int r = 0; r < 9; ++r) rot_out[i * 9 + r] = Rn[r];
        float t0 = u[3], t1 = u[4], t2 = u[5];
#pragma unroll
        for (int r = 0; r < 3; ++r)
            trans_out[i * 3 + r] = Ri[r * 3 + 0] * t0 + Ri[r * 3 + 1] * t1 + Ri[r * 3 + 2] * t2 + trans[i * 3 + r];
    }
}

// ---------------------------------------------------------------------------
// Loss
// ---------------------------------------------------------------------------
__global__ void loss_kernel(const float* __restrict__ rot_new, const float* __restrict__ trans_new,
                            const float* __restrict__ rot_truth, const float* __restrict__ trans_truth,
                            float* __restrict__ loss)
{
    int i = blockIdx.x;
    int t = threadIdx.x;
    __shared__ float red[256];
    float Rn[9], Rt[9];
#pragma unroll
    for (int r = 0; r < 9; ++r) { Rn[r] = rot_new[i * 9 + r]; Rt[r] = rot_truth[i * 9 + r]; }
    float ti0 = trans_new[i * 3 + 0], ti1 = trans_new[i * 3 + 1], ti2 = trans_new[i * 3 + 2];
    float tt0 = trans_truth[i * 3 + 0], tt1 = trans_truth[i * 3 + 1], tt2 = trans_truth[i * 3 + 2];
    float s = 0.f;
    for (int j = t; j < NRES; j += 256) {
        float db0 = trans_new[j * 3 + 0] - ti0;
        float db1 = trans_new[j * 3 + 1] - ti1;
        float db2 = trans_new[j * 3 + 2] - ti2;
        float dp0 = Rn[0] * db0 + Rn[3] * db1 + Rn[6] * db2;
        float dp1 = Rn[1] * db0 + Rn[4] * db1 + Rn[7] * db2;
        float dp2 = Rn[2] * db0 + Rn[5] * db1 + Rn[8] * db2;
        float eb0 = trans_truth[j * 3 + 0] - tt0;
        float eb1 = trans_truth[j * 3 + 1] - tt1;
        float eb2 = trans_truth[j * 3 + 2] - tt2;
        float dt0 = Rt[0] * eb0 + Rt[3] * eb1 + Rt[6] * eb2;
        float dt1 = Rt[1] * eb0 + Rt[4] * eb1 + Rt[7] * eb2;
        float dt2 = Rt[2] * eb0 + Rt[5] * eb1 + Rt[8] * eb2;
        float dx = dp0 - dt0, dy = dp1 - dt1, dz = dp2 - dt2;
        float dd = sqrtf(dx * dx + dy * dy + dz * dz + 1e-12f);
        s += fminf(dd, 10.f);
    }
    red[t] = s;
    __syncthreads();
    for (int k = 128; k > 0; k >>= 1) { if (t < k) red[t] += red[t + k]; __syncthreads(); }
    if (t == 0) atomicAdd(loss, red[0] * (1.f / (512.f * 512.f * 10.f)));
}

// ---------------------------------------------------------------------------
extern "C" void kernel_launch(void* const* d_in, const int* in_sizes, int n_in,
                              void* d_out, int out_size, void* d_ws, size_t ws_size,
                              hipStream_t stream)
{
    const float* single      = (const float*)d_in[0];
    const float* pair        = (const float*)d_in[1];
    const float* rot         = (const float*)d_in[2];
    const float* trans       = (const float*)d_in[3];
    const float* rot_truth   = (const float*)d_in[4];
    const float* trans_truth = (const float*)d_in[5];
    const float* Wq  = (const float*)d_in[6];
    const float* Wk  = (const float*)d_in[7];
    const float* Wv  = (const float*)d_in[8];
    const float* Wqp = (const float*)d_in[9];
    const float* Wkp = (const float*)d_in[10];
    const float* Wvp = (const float*)d_in[11];
    const float* Wb  = (const float*)d_in[12];
    const float* Wo  = (const float*)d_in[13];
    const float* bo  = (const float*)d_in[14];
    const float* gamma_raw = (const float*)d_in[15];
    const float* ln1_g = (const float*)d_in[16];
    const float* ln1_b = (const float*)d_in[17];
    const float* ln2_g = (const float*)d_in[18];
    const float* ln2_b = (const float*)d_in[19];
    const float* W1 = (const float*)d_in[20];
    const float* b1 = (const float*)d_in[21];
    const float* W2 = (const float*)d_in[22];
    const float* b2 = (const float*)d_in[23];
    const float* W3 = (const float*)d_in[24];
    const float* b3 = (const float*)d_in[25];
    const float* Wbu = (const float*)d_in[26];
    const float* bbu = (const float*)d_in[27];

    float* out = (float*)d_out;
    float* single_out = out;                   // 512*384
    float* rot_out    = out + 196608;          // 512*9
    float* trans_out  = out + 201216;          // 512*3
    float* loss_out   = out + 202752;          // 1

    float* ws = (float*)d_ws;
    float* proj   = ws;                         // 512*1152 = 589824
    float* gq     = proj   + 589824;            // 73728
    float* gv     = gq     + 73728;             // 147456
    float* sqq    = gv     + 147456;            // 6144
    float* kT     = sqq    + 6144;              // 98304
    float* gkT    = kT     + 98304;             // 73728
    float* sqkT   = gkT    + 73728;             // 6144
    float* Bp     = sqkT   + 6144;              // 384*1152 = 442368
    float* concat = Bp     + 442368;            // 512*2112 = 1081344
    float* out1   = concat + 1081344;           // 196608
    float* sln    = out1   + 196608;            // 196608
    float* h1     = sln    + 196608;            // 196608
    float* h2     = h1     + 196608;            // 196608

    dim3 b256(256);

    // 1. pack projection weights, fused projection GEMM
    pack_proj_kernel<<<dim3((CS * PRJ + 255) / 256), b256, 0, stream>>>(Wq, Wk, Wv, Wqp, Wkp, Wvp, Bp);
    gemm_tiled<<<dim3(8, PRJ / 64, 1), b256, 0, stream>>>(single, Bp, nullptr, nullptr, proj,
                                                          NRES, CS, PRJ, 0, CS);

    // 2. frames
    frames_kernel<<<dim3((NRES * NH + 255) / 256), b256, 0, stream>>>(proj, rot, trans,
                                                                      gq, gv, sqq, kT, gkT, sqkT);

    // 3. fused IPA attention (logits + softmax + o_pair + o_v + o_pt)
    ipa_fused_kernel<<<dim3(NRES), dim3(512), 0, stream>>>(pair, proj, gq, gv, kT, gkT,
                                                           sqq, sqkT, Wb, gamma_raw,
                                                           rot, trans, concat);

    // 4. ipa_out = concat @ Wo + bo + single  (k-split=4, atomic into pre-init)
    init_out1_kernel<<<dim3((NRES * CS + 255) / 256), b256, 0, stream>>>(bo, single, out1);
    gemm_tiled<<<dim3(8, CS / 64, 4), b256, 0, stream>>>(concat, Wo, nullptr, nullptr, out1,
                                                         NRES, OUT_DIM, CS, 0, 528);

    // 5. LN1 + FF + LN2
    ln_kernel<<<dim3(NRES), dim3(128), 0, stream>>>(out1, ln1_g, ln1_b, sln);
    gemm_tiled<<<dim3(8, CS / 64, 1), b256, 0, stream>>>(sln, W1, b1, nullptr, h1, NRES, CS, CS, 1, CS);
    gemm_tiled<<<dim3(8, CS / 64, 1), b256, 0, stream>>>(h1, W2, b2, nullptr, h2, NRES, CS, CS, 1, CS);
    gemm_tiled<<<dim3(8, CS / 64, 1), b256, 0, stream>>>(h2, W3, b3, sln, out1, NRES, CS, CS, 0, CS);
    ln_kernel<<<dim3(NRES), dim3(128), 0, stream>>>(out1, ln2_g, ln2_b, single_out);

    // 6. backbone + loss
    backbone_kernel<<<dim3(NRES), dim3(128), 0, stream>>>(single_out, Wbu, bbu, rot, trans, rot_out, trans_out);
    hipMemsetAsync(loss_out, 0, sizeof(float), stream);
    loss_kernel<<<dim3(NRES), b256, 0, stream>>>(rot_out, trans_out, rot_truth, trans_truth, loss_out);
}

// Round 7
// 316.344 us; speedup vs baseline: 1.7295x; 1.7295x over previous
//
#include <hip/hip_runtime.h>
#include <hip/hip_bf16.h>
#include <math.h>

#define NRES 512
#define CS 384
#define CZ 128
#define NH 12
#define PQ 4
#define PV 8
#define OUT_DIM 2112   // H*(C + 3*PV + PV + CZ)
#define PRJ 1152       // packed projection width: q192|k192|v192|qp144|kp144|vp288

typedef __attribute__((ext_vector_type(8))) short short8;
typedef __attribute__((ext_vector_type(4))) float f32x4;

__device__ __forceinline__ float softplusf(float x) { return log1pf(expf(x)); }

__device__ __forceinline__ unsigned short f2bf(float f) {
    union { float f; unsigned u; } v; v.f = f;
    unsigned r = v.u + 0x7FFF + ((v.u >> 16) & 1);
    return (unsigned short)(r >> 16);
}

// ---------------------------------------------------------------------------
// Pack 6 projection weight matrices into Bp[384][1152]
// ---------------------------------------------------------------------------
__global__ void pack_proj_kernel(const float* __restrict__ Wq, const float* __restrict__ Wk,
                                 const float* __restrict__ Wv, const float* __restrict__ Wqp,
                                 const float* __restrict__ Wkp, const float* __restrict__ Wvp,
                                 float* __restrict__ Bp)
{
    int x = blockIdx.x * blockDim.x + threadIdx.x;
    if (x >= CS * PRJ) return;
    int k = x / PRJ, c = x % PRJ;
    float v;
    if      (c < 192)  v = Wq [k * 192 + c];
    else if (c < 384)  v = Wk [k * 192 + (c - 192)];
    else if (c < 576)  v = Wv [k * 192 + (c - 384)];
    else if (c < 720)  v = Wqp[k * 144 + (c - 576)];
    else if (c < 864)  v = Wkp[k * 144 + (c - 720)];
    else               v = Wvp[k * 288 + (c - 864)];
    Bp[x] = v;
}

// ---------------------------------------------------------------------------
// Tiled f32 GEMM: BM=64, BN=64, BK=16, 256 threads, 4x4 micro-tile.
// reluA: apply relu to A elements on load (for k-split consumers of relu).
// If gridDim.z > 1: k-split partial, atomicAdd into pre-initialized C.
// ---------------------------------------------------------------------------
__global__ void gemm_tiled(const float* __restrict__ A, const float* __restrict__ B,
                           const float* __restrict__ bias, const float* __restrict__ res,
                           float* __restrict__ C, int M, int K, int Nc, int relu, int KS,
                           int reluA)
{
    __shared__ float As[16][68];
    __shared__ float Bs[16][64];
    int m0 = blockIdx.x * 64, n0 = blockIdx.y * 64;
    int kbeg = blockIdx.z * KS;
    int t = threadIdx.x;
    int tm = t >> 4, tn = t & 15;
    int lr = t >> 2, lc4 = t & 3;
    int br = t >> 4, bc4 = t & 15;
    float acc[4][4] = {{0.f}};

    for (int kt = kbeg; kt < kbeg + KS; kt += 16) {
        float4 a4 = *(const float4*)&A[(size_t)(m0 + lr) * K + kt + lc4 * 4];
        float4 b4 = *(const float4*)&B[(size_t)(kt + br) * Nc + n0 + bc4 * 4];
        if (reluA) {
            a4.x = fmaxf(a4.x, 0.f); a4.y = fmaxf(a4.y, 0.f);
            a4.z = fmaxf(a4.z, 0.f); a4.w = fmaxf(a4.w, 0.f);
        }
        As[lc4 * 4 + 0][lr] = a4.x;
        As[lc4 * 4 + 1][lr] = a4.y;
        As[lc4 * 4 + 2][lr] = a4.z;
        As[lc4 * 4 + 3][lr] = a4.w;
        *(float4*)&Bs[br][bc4 * 4] = b4;
        __syncthreads();
#pragma unroll
        for (int k = 0; k < 16; ++k) {
            float4 av = *(const float4*)&As[k][tm * 4];
            float4 bv = *(const float4*)&Bs[k][tn * 4];
            acc[0][0] = fmaf(av.x, bv.x, acc[0][0]); acc[0][1] = fmaf(av.x, bv.y, acc[0][1]);
            acc[0][2] = fmaf(av.x, bv.z, acc[0][2]); acc[0][3] = fmaf(av.x, bv.w, acc[0][3]);
            acc[1][0] = fmaf(av.y, bv.x, acc[1][0]); acc[1][1] = fmaf(av.y, bv.y, acc[1][1]);
            acc[1][2] = fmaf(av.y, bv.z, acc[1][2]); acc[1][3] = fmaf(av.y, bv.w, acc[1][3]);
            acc[2][0] = fmaf(av.z, bv.x, acc[2][0]); acc[2][1] = fmaf(av.z, bv.y, acc[2][1]);
            acc[2][2] = fmaf(av.z, bv.z, acc[2][2]); acc[2][3] = fmaf(av.z, bv.w, acc[2][3]);
            acc[3][0] = fmaf(av.w, bv.x, acc[3][0]); acc[3][1] = fmaf(av.w, bv.y, acc[3][1]);
            acc[3][2] = fmaf(av.w, bv.z, acc[3][2]); acc[3][3] = fmaf(av.w, bv.w, acc[3][3]);
        }
        __syncthreads();
    }

    if (gridDim.z > 1) {
#pragma unroll
        for (int r = 0; r < 4; ++r)
#pragma unroll
            for (int c = 0; c < 4; ++c)
                atomicAdd(&C[(size_t)(m0 + tm * 4 + r) * Nc + n0 + tn * 4 + c], acc[r][c]);
    } else {
#pragma unroll
        for (int r = 0; r < 4; ++r) {
            int row = m0 + tm * 4 + r;
            float4 v;
            float* vp = (float*)&v;
#pragma unroll
            for (int c = 0; c < 4; ++c) {
                int col = n0 + tn * 4 + c;
                float x = acc[r][c];
                if (bias) x += bias[col];
                if (res)  x += res[(size_t)row * Nc + col];
                if (relu) x = fmaxf(x, 0.f);
                vp[c] = x;
            }
            *(float4*)&C[(size_t)row * Nc + n0 + tn * 4] = v;
        }
    }
}

// ---------------------------------------------------------------------------
// init: out[x] = bias[x % Nc] (+ res[x])
// ---------------------------------------------------------------------------
__global__ void init_bias_kernel(const float* __restrict__ bias, const float* __restrict__ res,
                                 float* __restrict__ out, int total, int Nc)
{
    int x = blockIdx.x * blockDim.x + threadIdx.x;
    if (x >= total) return;
    float v = bias[x % Nc];
    if (res) v += res[x];
    out[x] = v;
}

// ---------------------------------------------------------------------------
// Frames: one thread per (n, h). Writes gq (n-major), gv (n-major), sqq,
// and j-major transposed kT[h][c][j], gkT[h][x][j], sqkT[h][j].
// ---------------------------------------------------------------------------
__global__ void frames_kernel(const float* __restrict__ proj, const float* __restrict__ rot,
                              const float* __restrict__ trans,
                              float* __restrict__ gq, float* __restrict__ gv,
                              float* __restrict__ sqq,
                              float* __restrict__ kT, float* __restrict__ gkT,
                              float* __restrict__ sqkT)
{
    int x = blockIdx.x * blockDim.x + threadIdx.x;
    if (x >= NRES * NH) return;
    int n = x / NH, h = x % NH;
    float R[9], t3[3];
#pragma unroll
    for (int r = 0; r < 9; ++r) R[r] = rot[n * 9 + r];
#pragma unroll
    for (int r = 0; r < 3; ++r) t3[r] = trans[n * 3 + r];
    const float* qp = proj + (size_t)n * PRJ + 576 + h * (PQ * 3);
    const float* kp = proj + (size_t)n * PRJ + 720 + h * (PQ * 3);
    const float* vp = proj + (size_t)n * PRJ + 864 + h * (PV * 3);
    const float* kk = proj + (size_t)n * PRJ + 192 + h * 16;

#pragma unroll
    for (int c = 0; c < 16; ++c) kT[(h * 16 + c) * NRES + n] = kk[c];

    float sq = 0.f, sk = 0.f;
#pragma unroll
    for (int p = 0; p < PQ; ++p) {
        const float* in = qp + p * 3;
        float* og = gq + (size_t)n * 144 + h * (PQ * 3) + p * 3;
#pragma unroll
        for (int a = 0; a < 3; ++a) {
            float g = R[a*3+0]*in[0] + R[a*3+1]*in[1] + R[a*3+2]*in[2] + t3[a];
            og[a] = g; sq += g * g;
        }
        const float* in2 = kp + p * 3;
#pragma unroll
        for (int a = 0; a < 3; ++a) {
            float g = R[a*3+0]*in2[0] + R[a*3+1]*in2[1] + R[a*3+2]*in2[2] + t3[a];
            gkT[(h * 12 + p * 3 + a) * NRES + n] = g;
            sk += g * g;
        }
    }
    sqq[n * NH + h] = sq;
    sqkT[h * NRES + n] = sk;
#pragma unroll
    for (int p = 0; p < PV; ++p) {
        const float* in = vp + p * 3;
        float* og = gv + (size_t)n * 288 + h * (PV * 3) + p * 3;
#pragma unroll
        for (int a = 0; a < 3; ++a)
            og[a] = R[a*3+0]*in[0] + R[a*3+1]*in[1] + R[a*3+2]*in[2] + t3[a];
    }
}

// ---------------------------------------------------------------------------
// Logits: grid (i=512, jt2=4), block 256 (4 waves); 2 x 64-j tiles per block.
// Bias via bf16 MFMA from swizzled LDS; qk/cross/d2 f32 with coalesced
// j-major loads. Writes pre-softmax L[i][h][j].
// ---------------------------------------------------------------------------
__global__ void logits_mfma_kernel(const float* __restrict__ pair, const float* __restrict__ proj,
                                   const float* __restrict__ gq, const float* __restrict__ kT,
                                   const float* __restrict__ gkT, const float* __restrict__ sqq,
                                   const float* __restrict__ sqkT, const float* __restrict__ Wb,
                                   const float* __restrict__ gamma_raw, float* __restrict__ L)
{
    __shared__ unsigned short pl[64 * 128];   // bf16 swizzled (16 KB)
    __shared__ float bias_s[64 * 17];
    __shared__ float qi[192], gqi[144], sqi[12], gam[12];

    int i = blockIdx.x, t = threadIdx.x;
    int lane = t & 63, w = t >> 6;

    short8 bfrag[4];
    {
        int col = lane & 15;
        int kb = (lane >> 4) * 8;
#pragma unroll
        for (int ks = 0; ks < 4; ++ks) {
            short8 f;
#pragma unroll
            for (int e = 0; e < 8; ++e) {
                float v = (col < NH) ? Wb[(ks * 32 + kb + e) * NH + col] : 0.f;
                f[e] = (short)f2bf(v);
            }
            bfrag[ks] = f;
        }
    }

    for (int x = t; x < 192; x += 256) qi[x] = proj[(size_t)i * PRJ + x];
    for (int x = t; x < 144; x += 256) gqi[x] = gq[(size_t)i * 144 + x];
    if (t < 12) { sqi[t] = sqq[i * 12 + t]; gam[t] = softplusf(gamma_raw[t]); }

    const float WLc = 0.57735026918962576f;
    const float WCc = 0.23570226039551584f;

    for (int sub = 0; sub < 2; ++sub) {
        int jt = blockIdx.y * 2 + sub;
        // stage pair tile
        const float* prow = pair + ((size_t)i * NRES + jt * 64) * CZ;
#pragma unroll
        for (int m = 0; m < 8; ++m) {
            int idx = m * 1024 + t * 4;
            int row = idx >> 7, kk = idx & 127;
            float4 v = *(const float4*)&prow[idx];
            unsigned b01 = (unsigned)f2bf(v.x) | ((unsigned)f2bf(v.y) << 16);
            unsigned b23 = (unsigned)f2bf(v.z) | ((unsigned)f2bf(v.w) << 16);
            int byte = row * 256 + ((kk * 2) ^ ((row & 7) << 4));
            *(uint2*)((char*)pl + byte) = make_uint2(b01, b23);
        }
        __syncthreads();
        // MFMA bias
        {
            f32x4 acc = {0.f, 0.f, 0.f, 0.f};
            int arow = w * 16 + (lane & 15);
            int kb2 = (lane >> 4) * 16;
#pragma unroll
            for (int ks = 0; ks < 4; ++ks) {
                int byte = arow * 256 + (((ks * 64) + kb2) ^ ((arow & 7) << 4));
                short8 afrag = *(const short8*)((const char*)pl + byte);
                acc = __builtin_amdgcn_mfma_f32_16x16x32_bf16(afrag, bfrag[ks], acc, 0, 0, 0);
            }
            int crow = w * 16 + (lane >> 4) * 4;
            int ccol = lane & 15;
#pragma unroll
            for (int r = 0; r < 4; ++r) bias_s[(crow + r) * 17 + ccol] = acc[r];
        }
        __syncthreads();
        // f32 epilogue
        int j = jt * 64 + lane;
#pragma unroll
        for (int hh = 0; hh < 3; ++hh) {
            int h = w * 3 + hh;
            float qk = 0.f;
#pragma unroll
            for (int c = 0; c < 16; ++c)
                qk = fmaf(qi[h * 16 + c], kT[(h * 16 + c) * NRES + j], qk);
            float cross = 0.f;
#pragma unroll
            for (int x = 0; x < 12; ++x)
                cross = fmaf(gqi[h * 12 + x], gkT[(h * 12 + x) * NRES + j], cross);
            float d2 = sqi[h] + sqkT[h * NRES + j] - 2.f * cross;
            float logit = WLc * (qk * 0.25f + bias_s[lane * 17 + h] - 0.5f * WCc * gam[h] * d2);
            L[((size_t)i * NH + h) * NRES + j] = logit;
        }
        __syncthreads();   // protect bias_s/pl before next tile
    }
}

// ---------------------------------------------------------------------------
// Softmax over j per (i,h) row, in place. grid = 6144, block = 256
// ---------------------------------------------------------------------------
__global__ void softmax_kernel(float* __restrict__ L)
{
    int row = blockIdx.x;
    float* p = L + (size_t)row * NRES;
    int t = threadIdx.x;
    __shared__ float red[256];
    float v0 = p[t], v1 = p[t + 256];
    red[t] = fmaxf(v0, v1);
    __syncthreads();
    for (int s = 128; s > 0; s >>= 1) { if (t < s) red[t] = fmaxf(red[t], red[t + s]); __syncthreads(); }
    float m = red[0];
    __syncthreads();
    float e0 = expf(v0 - m), e1 = expf(v1 - m);
    red[t] = e0 + e1;
    __syncthreads();
    for (int s = 128; s > 0; s >>= 1) { if (t < s) red[t] += red[t + s]; __syncthreads(); }
    float inv = 1.f / red[0];
    p[t] = e0 * inv;
    p[t + 256] = e1 * inv;
}

// ---------------------------------------------------------------------------
// o_pair: block per i, 768 threads = (32 z-quads x 12 heads x 2 j-halves)
// ---------------------------------------------------------------------------
__global__ __launch_bounds__(768) void opair_kernel(const float* __restrict__ pair,
                                                    const float* __restrict__ A,
                                                    float* __restrict__ concat)
{
    __shared__ float al[NH * NRES];     // 24 KB
    __shared__ float4 part[384];        // 6 KB
    int i = blockIdx.x, t = threadIdx.x;
    for (int x = t; x < NH * NRES / 4; x += 768)
        *(float4*)&al[x * 4] = *(const float4*)&A[(size_t)i * NH * NRES + x * 4];
    __syncthreads();
    int jh = (t >= 384) ? 1 : 0;
    int u = t - jh * 384;
    int zq = u & 31, h = u >> 5;
    float4 acc = {0.f, 0.f, 0.f, 0.f};
    const float* pr = pair + (size_t)i * NRES * CZ + (size_t)jh * 256 * CZ;
    const float* ah = al + h * NRES + jh * 256;
    for (int j = 0; j < 256; ++j) {
        float4 p4 = *(const float4*)&pr[(size_t)j * CZ + zq * 4];
        float a = ah[j];
        acc.x = fmaf(a, p4.x, acc.x);
        acc.y = fmaf(a, p4.y, acc.y);
        acc.z = fmaf(a, p4.z, acc.z);
        acc.w = fmaf(a, p4.w, acc.w);
    }
    if (t >= 384) part[u] = acc;
    __syncthreads();
    if (t < 384) {
        float4 o = part[t];
        o.x += acc.x; o.y += acc.y; o.z += acc.z; o.w += acc.w;
        *(float4*)&concat[(size_t)i * OUT_DIM + 576 + h * 128 + zq * 4] = o;
    }
}

// ---------------------------------------------------------------------------
// o_v, o_pt, local, norms -> concat[i, 0..575]. block per i, 1024 threads:
// unit = (elem 0..479, j-half); elem<192: o_v, else o_pt.
// ---------------------------------------------------------------------------
__global__ __launch_bounds__(1024) void ov_opt_kernel(const float* __restrict__ A,
                                                      const float* __restrict__ proj,
                                                      const float* __restrict__ gv,
                                                      const float* __restrict__ rot,
                                                      const float* __restrict__ trans,
                                                      float* __restrict__ concat)
{
    __shared__ float al[NH * NRES];    // 24 KB
    __shared__ float part[960];
    __shared__ float opt[NH * PV * 3];
    int i = blockIdx.x, t = threadIdx.x;
    for (int x = t; x < NH * NRES / 4; x += 1024)
        *(float4*)&al[x * 4] = *(const float4*)&A[(size_t)i * NH * NRES + x * 4];
    __syncthreads();

    if (t < 960) {
        int jh = (t >= 480) ? 1 : 0;
        int elem = t - jh * 480;
        float acc = 0.f;
        if (elem < 192) {
            int h = elem >> 4;
            const float* ah = al + h * NRES + jh * 256;
            const float* pv = proj + (size_t)(jh * 256) * PRJ + 384 + elem;
            for (int j = 0; j < 256; ++j) { acc = fmaf(ah[j], *pv, acc); pv += PRJ; }
        } else {
            int e = elem - 192;
            int h = e / 24;
            const float* ah = al + h * NRES + jh * 256;
            const float* pv = gv + (size_t)(jh * 256) * 288 + e;
            for (int j = 0; j < 256; ++j) { acc = fmaf(ah[j], *pv, acc); pv += 288; }
        }
        part[t] = acc;
    }
    __syncthreads();
    if (t < 480) {
        float v = part[t] + part[t + 480];
        if (t < 192) concat[(size_t)i * OUT_DIM + t] = v;
        else opt[t - 192] = v;
    }
    __syncthreads();
    if (t < 96) {
        int h = t >> 3, p = t & 7;
        float b0 = opt[h * 24 + p * 3 + 0] - trans[i * 3 + 0];
        float b1 = opt[h * 24 + p * 3 + 1] - trans[i * 3 + 1];
        float b2 = opt[h * 24 + p * 3 + 2] - trans[i * 3 + 2];
        const float* Ri = rot + i * 9;
        float l0 = Ri[0] * b0 + Ri[3] * b1 + Ri[6] * b2;
        float l1 = Ri[1] * b0 + Ri[4] * b1 + Ri[7] * b2;
        float l2 = Ri[2] * b0 + Ri[5] * b1 + Ri[8] * b2;
        float* c = concat + (size_t)i * OUT_DIM;
        c[192 + h * 24 + p * 3 + 0] = l0;
        c[192 + h * 24 + p * 3 + 1] = l1;
        c[192 + h * 24 + p * 3 + 2] = l2;
        c[480 + h * 8 + p] = sqrtf(l0 * l0 + l1 * l1 + l2 * l2 + 1e-8f);
    }
}

// ---------------------------------------------------------------------------
// LayerNorm over 384
// ---------------------------------------------------------------------------
__global__ void ln_kernel(const float* __restrict__ x, const float* __restrict__ g,
                          const float* __restrict__ b, float* __restrict__ y)
{
    int i = blockIdx.x, t = threadIdx.x;
    const float* xr = x + (size_t)i * CS;
    float a0 = xr[t], a1 = xr[t + 128], a2 = xr[t + 256];
    __shared__ float red[128];
    red[t] = a0 + a1 + a2;
    __syncthreads();
    for (int s = 64; s > 0; s >>= 1) { if (t < s) red[t] += red[t + s]; __syncthreads(); }
    float mean = red[0] * (1.f / CS);
    __syncthreads();
    float d0 = a0 - mean, d1 = a1 - mean, d2 = a2 - mean;
    red[t] = d0 * d0 + d1 * d1 + d2 * d2;
    __syncthreads();
    for (int s = 64; s > 0; s >>= 1) { if (t < s) red[t] += red[t + s]; __syncthreads(); }
    float rstd = rsqrtf(red[0] * (1.f / CS) + 1e-5f);
    float* yr = y + (size_t)i * CS;
    yr[t]       = d0 * rstd * g[t]       + b[t];
    yr[t + 128] = d1 * rstd * g[t + 128] + b[t + 128];
    yr[t + 256] = d2 * rstd * g[t + 256] + b[t + 256];
}

// ---------------------------------------------------------------------------
// Backbone: one block (128 thr) per residue; LDS reduce over 6 comps.
// ---------------------------------------------------------------------------
__global__ void backbone_kernel(const float* __restrict__ sfin, const float* __restrict__ Wbu,
                                const float* __restrict__ bbu, const float* __restrict__ rot,
                                const float* __restrict__ trans, float* __restrict__ rot_out,
                                float* __restrict__ trans_out)
{
    int i = blockIdx.x, t = threadIdx.x;
    float part[6] = {0.f, 0.f, 0.f, 0.f, 0.f, 0.f};
    for (int k = t; k < CS; k += 128) {
        float s = sfin[(size_t)i * CS + k];
        const float* wr = Wbu + k * 6;
#pragma unroll
        for (int c = 0; c < 6; ++c) part[c] = fmaf(s, wr[c], part[c]);
    }
    __shared__ float red[6][128];
#pragma unroll
    for (int c = 0; c < 6; ++c) red[c][t] = part[c];
    __syncthreads();
    for (int s = 64; s > 0; s >>= 1) {
        if (t < s) {
#pragma unroll
            for (int c = 0; c < 6; ++c) red[c][t] += red[c][t + s];
        }
        __syncthreads();
    }
    if (t == 0) {
        float u[6];
#pragma unroll
        for (int c = 0; c < 6; ++c) u[c] = red[c][0] + bbu[c];
        float a = 1.f, b = u[0], c2 = u[1], d = u[2];
        float inv = rsqrtf(a * a + b * b + c2 * c2 + d * d);
        a *= inv; b *= inv; c2 *= inv; d *= inv;
        float R[9] = { a*a + b*b - c2*c2 - d*d, 2.f*(b*c2 - a*d),        2.f*(b*d + a*c2),
                       2.f*(b*c2 + a*d),        a*a - b*b + c2*c2 - d*d, 2.f*(c2*d - a*b),
                       2.f*(b*d - a*c2),        2.f*(c2*d + a*b),        a*a - b*b - c2*c2 + d*d };
        const float* Ri = rot + i * 9;
        float Rn[9];
#pragma unroll
        for (int r = 0; r < 3; ++r)
#pragma unroll
            for (int cc = 0; cc < 3; ++cc) {
                float s2 = 0.f;
#pragma unroll
                for (int kk = 0; kk < 3; ++kk) s2 += Ri[r * 3 + kk] * R[kk * 3 + cc];
                Rn[r * 3 + cc] = s2;
            }
#pragma unroll
        for (int r = 0; r < 9; ++r) rot_out[i * 9 + r] = Rn[r];
        float t0 = u[3], t1 = u[4], t2 = u[5];
#pragma unroll
        for (int r = 0; r < 3; ++r)
            trans_out[i * 3 + r] = Ri[r * 3 + 0] * t0 + Ri[r * 3 + 1] * t1 + Ri[r * 3 + 2] * t2 + trans[i * 3 + r];
    }
}

// ---------------------------------------------------------------------------
// Loss
// ---------------------------------------------------------------------------
__global__ void loss_kernel(const float* __restrict__ rot_new, const float* __restrict__ trans_new,
                            const float* __restrict__ rot_truth, const float* __restrict__ trans_truth,
                            float* __restrict__ loss)
{
    int i = blockIdx.x;
    int t = threadIdx.x;
    __shared__ float red[256];
    float Rn[9], Rt[9];
#pragma unroll
    for (int r = 0; r < 9; ++r) { Rn[r] = rot_new[i * 9 + r]; Rt[r] = rot_truth[i * 9 + r]; }
    float ti0 = trans_new[i * 3 + 0], ti1 = trans_new[i * 3 + 1], ti2 = trans_new[i * 3 + 2];
    float tt0 = trans_truth[i * 3 + 0], tt1 = trans_truth[i * 3 + 1], tt2 = trans_truth[i * 3 + 2];
    float s = 0.f;
    for (int j = t; j < NRES; j += 256) {
        float db0 = trans_new[j * 3 + 0] - ti0;
        float db1 = trans_new[j * 3 + 1] - ti1;
        float db2 = trans_new[j * 3 + 2] - ti2;
        float dp0 = Rn[0] * db0 + Rn[3] * db1 + Rn[6] * db2;
        float dp1 = Rn[1] * db0 + Rn[4] * db1 + Rn[7] * db2;
        float dp2 = Rn[2] * db0 + Rn[5] * db1 + Rn[8] * db2;
        float eb0 = trans_truth[j * 3 + 0] - tt0;
        float eb1 = trans_truth[j * 3 + 1] - tt1;
        float eb2 = trans_truth[j * 3 + 2] - tt2;
        float dt0 = Rt[0] * eb0 + Rt[3] * eb1 + Rt[6] * eb2;
        float dt1 = Rt[1] * eb0 + Rt[4] * eb1 + Rt[7] * eb2;
        float dt2 = Rt[2] * eb0 + Rt[5] * eb1 + Rt[8] * eb2;
        float dx = dp0 - dt0, dy = dp1 - dt1, dz = dp2 - dt2;
        float dd = sqrtf(dx * dx + dy * dy + dz * dz + 1e-12f);
        s += fminf(dd, 10.f);
    }
    red[t] = s;
    __syncthreads();
    for (int k = 128; k > 0; k >>= 1) { if (t < k) red[t] += red[t + k]; __syncthreads(); }
    if (t == 0) atomicAdd(loss, red[0] * (1.f / (512.f * 512.f * 10.f)));
}

// ---------------------------------------------------------------------------
extern "C" void kernel_launch(void* const* d_in, const int* in_sizes, int n_in,
                              void* d_out, int out_size, void* d_ws, size_t ws_size,
                              hipStream_t stream)
{
    const float* single      = (const float*)d_in[0];
    const float* pair        = (const float*)d_in[1];
    const float* rot         = (const float*)d_in[2];
    const float* trans       = (const float*)d_in[3];
    const float* rot_truth   = (const float*)d_in[4];
    const float* trans_truth = (const float*)d_in[5];
    const float* Wq  = (const float*)d_in[6];
    const float* Wk  = (const float*)d_in[7];
    const float* Wv  = (const float*)d_in[8];
    const float* Wqp = (const float*)d_in[9];
    const float* Wkp = (const float*)d_in[10];
    const float* Wvp = (const float*)d_in[11];
    const float* Wb  = (const float*)d_in[12];
    const float* Wo  = (const float*)d_in[13];
    const float* bo  = (const float*)d_in[14];
    const float* gamma_raw = (const float*)d_in[15];
    const float* ln1_g = (const float*)d_in[16];
    const float* ln1_b = (const float*)d_in[17];
    const float* ln2_g = (const float*)d_in[18];
    const float* ln2_b = (const float*)d_in[19];
    const float* W1 = (const float*)d_in[20];
    const float* b1 = (const float*)d_in[21];
    const float* W2 = (const float*)d_in[22];
    const float* b2 = (const float*)d_in[23];
    const float* W3 = (const float*)d_in[24];
    const float* b3 = (const float*)d_in[25];
    const float* Wbu = (const float*)d_in[26];
    const float* bbu = (const float*)d_in[27];

    float* out = (float*)d_out;
    float* single_out = out;                   // 512*384
    float* rot_out    = out + 196608;          // 512*9
    float* trans_out  = out + 201216;          // 512*3
    float* loss_out   = out + 202752;          // 1

    float* ws = (float*)d_ws;
    float* proj   = ws;                         // 512*1152 = 589824
    float* gq     = proj   + 589824;            // 73728
    float* gv     = gq     + 73728;             // 147456
    float* sqq    = gv     + 147456;            // 6144
    float* kT     = sqq    + 6144;              // 98304
    float* gkT    = kT     + 98304;             // 73728
    float* sqkT   = gkT    + 73728;             // 6144
    float* Amat   = sqkT   + 6144;              // 3145728
    float* Bp     = Amat;                       // alias (used only before logits)
    float* concat = Amat   + 3145728;           // 1081344
    float* out1   = concat + 1081344;           // 196608 (Wo result, later FF result)
    float* sln    = out1   + 196608;            // 196608
    float* h1     = sln    + 196608;            // 196608
    float* h2     = h1     + 196608;            // 196608

    dim3 b256(256);

    // 1. pack projection weights; zero proj; fused projection GEMM (k-split 2)
    pack_proj_kernel<<<dim3((CS * PRJ + 255) / 256), b256, 0, stream>>>(Wq, Wk, Wv, Wqp, Wkp, Wvp, Bp);
    hipMemsetAsync(proj, 0, (size_t)NRES * PRJ * sizeof(float), stream);
    gemm_tiled<<<dim3(8, PRJ / 64, 2), b256, 0, stream>>>(single, Bp, nullptr, nullptr, proj,
                                                          NRES, CS, PRJ, 0, 192, 0);

    // 2. frames
    frames_kernel<<<dim3((NRES * NH + 255) / 256), b256, 0, stream>>>(proj, rot, trans,
                                                                      gq, gv, sqq, kT, gkT, sqkT);

    // 3. logits (2 tiles per block) + softmax
    logits_mfma_kernel<<<dim3(NRES, 4), b256, 0, stream>>>(pair, proj, gq, kT, gkT, sqq, sqkT,
                                                           Wb, gamma_raw, Amat);
    softmax_kernel<<<dim3(NRES * NH), b256, 0, stream>>>(Amat);

    // 4. attention outputs (j-split in block)
    opair_kernel<<<dim3(NRES), dim3(768), 0, stream>>>(pair, Amat, concat);
    ov_opt_kernel<<<dim3(NRES), dim3(1024), 0, stream>>>(Amat, proj, gv, rot, trans, concat);

    // 5. ipa_out = concat @ Wo + bo + single  (k-split 4, atomic into pre-init)
    init_bias_kernel<<<dim3((NRES * CS + 255) / 256), b256, 0, stream>>>(bo, single, out1,
                                                                         NRES * CS, CS);
    gemm_tiled<<<dim3(8, CS / 64, 4), b256, 0, stream>>>(concat, Wo, nullptr, nullptr, out1,
                                                         NRES, OUT_DIM, CS, 0, 528, 0);

    // 6. LN1 + FF (k-split 4, relu folded into consumer A-load) + LN2
    ln_kernel<<<dim3(NRES), dim3(128), 0, stream>>>(out1, ln1_g, ln1_b, sln);
    init_bias_kernel<<<dim3((NRES * CS + 255) / 256), b256, 0, stream>>>(b1, nullptr, h1,
                                                                         NRES * CS, CS);
    init_bias_kernel<<<dim3((NRES * CS + 255) / 256), b256, 0, stream>>>(b2, nullptr, h2,
                                                                         NRES * CS, CS);
    gemm_tiled<<<dim3(8, CS / 64, 4), b256, 0, stream>>>(sln, W1, nullptr, nullptr, h1,
                                                         NRES, CS, CS, 0, 96, 0);
    gemm_tiled<<<dim3(8, CS / 64, 4), b256, 0, stream>>>(h1, W2, nullptr, nullptr, h2,
                                                         NRES, CS, CS, 0, 96, 1);
    init_bias_kernel<<<dim3((NRES * CS + 255) / 256), b256, 0, stream>>>(b3, sln, out1,
                                                                         NRES * CS, CS);
    gemm_tiled<<<dim3(8, CS / 64, 4), b256, 0, stream>>>(h2, W3, nullptr, nullptr, out1,
                                                         NRES, CS, CS, 0, 96, 1);
    ln_kernel<<<dim3(NRES), dim3(128), 0, stream>>>(out1, ln2_g, ln2_b, single_out);

    // 7. backbone + loss
    backbone_kernel<<<dim3(NRES), dim3(128), 0, stream>>>(single_out, Wbu, bbu, rot, trans,
                                                          rot_out, trans_out);
    hipMemsetAsync(loss_out, 0, sizeof(float), stream);
    loss_kernel<<<dim3(NRES), b256, 0, stream>>>(rot_out, trans_out, rot_truth, trans_truth, loss_out);
}

// Round 8
// 286.641 us; speedup vs baseline: 1.9087x; 1.1036x over previous
//
#include <hip/hip_runtime.h>
#include <hip/hip_bf16.h>
#include <math.h>

#define NRES 512
#define CS 384
#define CZ 128
#define NH 12
#define PQ 4
#define PV 8
#define OUT_DIM 2112   // H*(C + 3*PV + PV + CZ)
#define PRJ 1152       // packed projection width: q192|k192|v192|qp144|kp144|vp288

typedef __attribute__((ext_vector_type(8))) short short8;
typedef __attribute__((ext_vector_type(4))) float f32x4;

__device__ __forceinline__ float softplusf(float x) { return log1pf(expf(x)); }

__device__ __forceinline__ unsigned short f2bf(float f) {
    union { float f; unsigned u; } v; v.f = f;
    unsigned r = v.u + 0x7FFF + ((v.u >> 16) & 1);
    return (unsigned short)(r >> 16);
}

__device__ __forceinline__ unsigned cvt_pk_bf16(float lo, float hi) {
    unsigned r;
    asm volatile("v_cvt_pk_bf16_f32 %0, %1, %2" : "=v"(r) : "v"(lo), "v"(hi));
    return r;
}

// ---------------------------------------------------------------------------
// Pack 6 projection weight matrices into Bp[384][1152]
// ---------------------------------------------------------------------------
__global__ void pack_proj_kernel(const float* __restrict__ Wq, const float* __restrict__ Wk,
                                 const float* __restrict__ Wv, const float* __restrict__ Wqp,
                                 const float* __restrict__ Wkp, const float* __restrict__ Wvp,
                                 float* __restrict__ Bp)
{
    int x = blockIdx.x * blockDim.x + threadIdx.x;
    if (x >= CS * PRJ) return;
    int k = x / PRJ, c = x % PRJ;
    float v;
    if      (c < 192)  v = Wq [k * 192 + c];
    else if (c < 384)  v = Wk [k * 192 + (c - 192)];
    else if (c < 576)  v = Wv [k * 192 + (c - 384)];
    else if (c < 720)  v = Wqp[k * 144 + (c - 576)];
    else if (c < 864)  v = Wkp[k * 144 + (c - 720)];
    else               v = Wvp[k * 288 + (c - 864)];
    Bp[x] = v;
}

// ---------------------------------------------------------------------------
// Tiled f32 GEMM: BM=64, BN=64, BK=16, 256 threads, 4x4 micro-tile.
// reluA: apply relu to A elements on load (for k-split consumers of relu).
// If gridDim.z > 1: k-split partial, atomicAdd into pre-initialized C.
// ---------------------------------------------------------------------------
__global__ void gemm_tiled(const float* __restrict__ A, const float* __restrict__ B,
                           const float* __restrict__ bias, const float* __restrict__ res,
                           float* __restrict__ C, int M, int K, int Nc, int relu, int KS,
                           int reluA)
{
    __shared__ float As[16][68];
    __shared__ float Bs[16][64];
    int m0 = blockIdx.x * 64, n0 = blockIdx.y * 64;
    int kbeg = blockIdx.z * KS;
    int t = threadIdx.x;
    int tm = t >> 4, tn = t & 15;
    int lr = t >> 2, lc4 = t & 3;
    int br = t >> 4, bc4 = t & 15;
    float acc[4][4] = {{0.f}};

    for (int kt = kbeg; kt < kbeg + KS; kt += 16) {
        float4 a4 = *(const float4*)&A[(size_t)(m0 + lr) * K + kt + lc4 * 4];
        float4 b4 = *(const float4*)&B[(size_t)(kt + br) * Nc + n0 + bc4 * 4];
        if (reluA) {
            a4.x = fmaxf(a4.x, 0.f); a4.y = fmaxf(a4.y, 0.f);
            a4.z = fmaxf(a4.z, 0.f); a4.w = fmaxf(a4.w, 0.f);
        }
        As[lc4 * 4 + 0][lr] = a4.x;
        As[lc4 * 4 + 1][lr] = a4.y;
        As[lc4 * 4 + 2][lr] = a4.z;
        As[lc4 * 4 + 3][lr] = a4.w;
        *(float4*)&Bs[br][bc4 * 4] = b4;
        __syncthreads();
#pragma unroll
        for (int k = 0; k < 16; ++k) {
            float4 av = *(const float4*)&As[k][tm * 4];
            float4 bv = *(const float4*)&Bs[k][tn * 4];
            acc[0][0] = fmaf(av.x, bv.x, acc[0][0]); acc[0][1] = fmaf(av.x, bv.y, acc[0][1]);
            acc[0][2] = fmaf(av.x, bv.z, acc[0][2]); acc[0][3] = fmaf(av.x, bv.w, acc[0][3]);
            acc[1][0] = fmaf(av.y, bv.x, acc[1][0]); acc[1][1] = fmaf(av.y, bv.y, acc[1][1]);
            acc[1][2] = fmaf(av.y, bv.z, acc[1][2]); acc[1][3] = fmaf(av.y, bv.w, acc[1][3]);
            acc[2][0] = fmaf(av.z, bv.x, acc[2][0]); acc[2][1] = fmaf(av.z, bv.y, acc[2][1]);
            acc[2][2] = fmaf(av.z, bv.z, acc[2][2]); acc[2][3] = fmaf(av.z, bv.w, acc[2][3]);
            acc[3][0] = fmaf(av.w, bv.x, acc[3][0]); acc[3][1] = fmaf(av.w, bv.y, acc[3][1]);
            acc[3][2] = fmaf(av.w, bv.z, acc[3][2]); acc[3][3] = fmaf(av.w, bv.w, acc[3][3]);
        }
        __syncthreads();
    }

    if (gridDim.z > 1) {
#pragma unroll
        for (int r = 0; r < 4; ++r)
#pragma unroll
            for (int c = 0; c < 4; ++c)
                atomicAdd(&C[(size_t)(m0 + tm * 4 + r) * Nc + n0 + tn * 4 + c], acc[r][c]);
    } else {
#pragma unroll
        for (int r = 0; r < 4; ++r) {
            int row = m0 + tm * 4 + r;
            float4 v;
            float* vp = (float*)&v;
#pragma unroll
            for (int c = 0; c < 4; ++c) {
                int col = n0 + tn * 4 + c;
                float x = acc[r][c];
                if (bias) x += bias[col];
                if (res)  x += res[(size_t)row * Nc + col];
                if (relu) x = fmaxf(x, 0.f);
                vp[c] = x;
            }
            *(float4*)&C[(size_t)row * Nc + n0 + tn * 4] = v;
        }
    }
}

// ---------------------------------------------------------------------------
// init: out[x] = bias[x % Nc] (+ res[x])
// ---------------------------------------------------------------------------
__global__ void init_bias_kernel(const float* __restrict__ bias, const float* __restrict__ res,
                                 float* __restrict__ out, int total, int Nc)
{
    int x = blockIdx.x * blockDim.x + threadIdx.x;
    if (x >= total) return;
    float v = bias[x % Nc];
    if (res) v += res[x];
    out[x] = v;
}

// ---------------------------------------------------------------------------
// Frames: one thread per (n, h). Writes gq (n-major), gv (n-major), sqq,
// and j-major transposed kT[h][c][j], gkT[h][x][j], sqkT[h][j].
// ---------------------------------------------------------------------------
__global__ void frames_kernel(const float* __restrict__ proj, const float* __restrict__ rot,
                              const float* __restrict__ trans,
                              float* __restrict__ gq, float* __restrict__ gv,
                              float* __restrict__ sqq,
                              float* __restrict__ kT, float* __restrict__ gkT,
                              float* __restrict__ sqkT)
{
    int x = blockIdx.x * blockDim.x + threadIdx.x;
    if (x >= NRES * NH) return;
    int n = x / NH, h = x % NH;
    float R[9], t3[3];
#pragma unroll
    for (int r = 0; r < 9; ++r) R[r] = rot[n * 9 + r];
#pragma unroll
    for (int r = 0; r < 3; ++r) t3[r] = trans[n * 3 + r];
    const float* qp = proj + (size_t)n * PRJ + 576 + h * (PQ * 3);
    const float* kp = proj + (size_t)n * PRJ + 720 + h * (PQ * 3);
    const float* vp = proj + (size_t)n * PRJ + 864 + h * (PV * 3);
    const float* kk = proj + (size_t)n * PRJ + 192 + h * 16;

#pragma unroll
    for (int c = 0; c < 16; ++c) kT[(h * 16 + c) * NRES + n] = kk[c];

    float sq = 0.f, sk = 0.f;
#pragma unroll
    for (int p = 0; p < PQ; ++p) {
        const float* in = qp + p * 3;
        float* og = gq + (size_t)n * 144 + h * (PQ * 3) + p * 3;
#pragma unroll
        for (int a = 0; a < 3; ++a) {
            float g = R[a*3+0]*in[0] + R[a*3+1]*in[1] + R[a*3+2]*in[2] + t3[a];
            og[a] = g; sq += g * g;
        }
        const float* in2 = kp + p * 3;
#pragma unroll
        for (int a = 0; a < 3; ++a) {
            float g = R[a*3+0]*in2[0] + R[a*3+1]*in2[1] + R[a*3+2]*in2[2] + t3[a];
            gkT[(h * 12 + p * 3 + a) * NRES + n] = g;
            sk += g * g;
        }
    }
    sqq[n * NH + h] = sq;
    sqkT[h * NRES + n] = sk;
#pragma unroll
    for (int p = 0; p < PV; ++p) {
        const float* in = vp + p * 3;
        float* og = gv + (size_t)n * 288 + h * (PV * 3) + p * 3;
#pragma unroll
        for (int a = 0; a < 3; ++a)
            og[a] = R[a*3+0]*in[0] + R[a*3+1]*in[1] + R[a*3+2]*in[2] + t3[a];
    }
}

// ---------------------------------------------------------------------------
// Logits: grid (i=512, jt=8), block 256 (4 waves), one 64-j tile per block.
// Bias via bf16 MFMA from swizzled LDS (v_cvt_pk_bf16_f32 packing);
// qk/cross/d2 f32 with coalesced j-major loads. Writes pre-softmax L.
// ---------------------------------------------------------------------------
__global__ void logits_mfma_kernel(const float* __restrict__ pair, const float* __restrict__ proj,
                                   const float* __restrict__ gq, const float* __restrict__ kT,
                                   const float* __restrict__ gkT, const float* __restrict__ sqq,
                                   const float* __restrict__ sqkT, const float* __restrict__ Wb,
                                   const float* __restrict__ gamma_raw, float* __restrict__ L)
{
    __shared__ unsigned short pl[64 * 128];   // bf16 swizzled (16 KB)
    __shared__ float bias_s[64 * 17];
    __shared__ float qi[192], gqi[144], sqi[12], gam[12];

    int i = blockIdx.x, jt = blockIdx.y, t = threadIdx.x;
    int lane = t & 63, w = t >> 6;

    short8 bfrag[4];
    {
        int col = lane & 15;
        int kb = (lane >> 4) * 8;
#pragma unroll
        for (int ks = 0; ks < 4; ++ks) {
            short8 f;
#pragma unroll
            for (int e = 0; e < 8; ++e) {
                float v = (col < NH) ? Wb[(ks * 32 + kb + e) * NH + col] : 0.f;
                f[e] = (short)f2bf(v);
            }
            bfrag[ks] = f;
        }
    }

    for (int x = t; x < 192; x += 256) qi[x] = proj[(size_t)i * PRJ + x];
    for (int x = t; x < 144; x += 256) gqi[x] = gq[(size_t)i * 144 + x];
    if (t < 12) { sqi[t] = sqq[i * 12 + t]; gam[t] = softplusf(gamma_raw[t]); }

    // stage pair tile -> bf16 swizzled LDS (cvt_pk packing)
    const float* prow = pair + ((size_t)i * NRES + jt * 64) * CZ;
#pragma unroll
    for (int m = 0; m < 8; ++m) {
        int idx = m * 1024 + t * 4;
        int row = idx >> 7, kk = idx & 127;
        float4 v = *(const float4*)&prow[idx];
        unsigned b01 = cvt_pk_bf16(v.x, v.y);
        unsigned b23 = cvt_pk_bf16(v.z, v.w);
        int byte = row * 256 + ((kk * 2) ^ ((row & 7) << 4));
        *(uint2*)((char*)pl + byte) = make_uint2(b01, b23);
    }
    __syncthreads();

    // MFMA bias
    {
        f32x4 acc = {0.f, 0.f, 0.f, 0.f};
        int arow = w * 16 + (lane & 15);
        int kb2 = (lane >> 4) * 16;
#pragma unroll
        for (int ks = 0; ks < 4; ++ks) {
            int byte = arow * 256 + (((ks * 64) + kb2) ^ ((arow & 7) << 4));
            short8 afrag = *(const short8*)((const char*)pl + byte);
            acc = __builtin_amdgcn_mfma_f32_16x16x32_bf16(afrag, bfrag[ks], acc, 0, 0, 0);
        }
        int crow = w * 16 + (lane >> 4) * 4;
        int ccol = lane & 15;
#pragma unroll
        for (int r = 0; r < 4; ++r) bias_s[(crow + r) * 17 + ccol] = acc[r];
    }
    __syncthreads();

    // f32 epilogue
    const float WLc = 0.57735026918962576f;
    const float WCc = 0.23570226039551584f;
    int j = jt * 64 + lane;
#pragma unroll
    for (int hh = 0; hh < 3; ++hh) {
        int h = w * 3 + hh;
        float qk = 0.f;
#pragma unroll
        for (int c = 0; c < 16; ++c)
            qk = fmaf(qi[h * 16 + c], kT[(h * 16 + c) * NRES + j], qk);
        float cross = 0.f;
#pragma unroll
        for (int x = 0; x < 12; ++x)
            cross = fmaf(gqi[h * 12 + x], gkT[(h * 12 + x) * NRES + j], cross);
        float d2 = sqi[h] + sqkT[h * NRES + j] - 2.f * cross;
        float logit = WLc * (qk * 0.25f + bias_s[lane * 17 + h] - 0.5f * WCc * gam[h] * d2);
        L[((size_t)i * NH + h) * NRES + j] = logit;
    }
}

// ---------------------------------------------------------------------------
// Softmax over j per (i,h) row, in place. grid = 6144, block = 256
// ---------------------------------------------------------------------------
__global__ void softmax_kernel(float* __restrict__ L)
{
    int row = blockIdx.x;
    float* p = L + (size_t)row * NRES;
    int t = threadIdx.x;
    __shared__ float red[256];
    float v0 = p[t], v1 = p[t + 256];
    red[t] = fmaxf(v0, v1);
    __syncthreads();
    for (int s = 128; s > 0; s >>= 1) { if (t < s) red[t] = fmaxf(red[t], red[t + s]); __syncthreads(); }
    float m = red[0];
    __syncthreads();
    float e0 = expf(v0 - m), e1 = expf(v1 - m);
    red[t] = e0 + e1;
    __syncthreads();
    for (int s = 128; s > 0; s >>= 1) { if (t < s) red[t] += red[t + s]; __syncthreads(); }
    float inv = 1.f / red[0];
    p[t] = e0 * inv;
    p[t + 256] = e1 * inv;
}

// ---------------------------------------------------------------------------
// o_pair: block per i, 768 threads = (32 z-quads x 12 heads x 2 j-halves)
// ---------------------------------------------------------------------------
__global__ __launch_bounds__(768) void opair_kernel(const float* __restrict__ pair,
                                                    const float* __restrict__ A,
                                                    float* __restrict__ concat)
{
    __shared__ float al[NH * NRES];     // 24 KB
    __shared__ float4 part[384];        // 6 KB
    int i = blockIdx.x, t = threadIdx.x;
    for (int x = t; x < NH * NRES / 4; x += 768)
        *(float4*)&al[x * 4] = *(const float4*)&A[(size_t)i * NH * NRES + x * 4];
    __syncthreads();
    int jh = (t >= 384) ? 1 : 0;
    int u = t - jh * 384;
    int zq = u & 31, h = u >> 5;
    float4 acc = {0.f, 0.f, 0.f, 0.f};
    const float* pr = pair + (size_t)i * NRES * CZ + (size_t)jh * 256 * CZ;
    const float* ah = al + h * NRES + jh * 256;
    for (int j = 0; j < 256; ++j) {
        float4 p4 = *(const float4*)&pr[(size_t)j * CZ + zq * 4];
        float a = ah[j];
        acc.x = fmaf(a, p4.x, acc.x);
        acc.y = fmaf(a, p4.y, acc.y);
        acc.z = fmaf(a, p4.z, acc.z);
        acc.w = fmaf(a, p4.w, acc.w);
    }
    if (t >= 384) part[u] = acc;
    __syncthreads();
    if (t < 384) {
        float4 o = part[t];
        o.x += acc.x; o.y += acc.y; o.z += acc.z; o.w += acc.w;
        *(float4*)&concat[(size_t)i * OUT_DIM + 576 + h * 128 + zq * 4] = o;
    }
}

// ---------------------------------------------------------------------------
// o_v, o_pt, local, norms -> concat[i, 0..575]. block per i, 1024 threads:
// unit = (elem 0..479, j-half); elem<192: o_v, else o_pt.
// ---------------------------------------------------------------------------
__global__ __launch_bounds__(1024) void ov_opt_kernel(const float* __restrict__ A,
                                                      const float* __restrict__ proj,
                                                      const float* __restrict__ gv,
                                                      const float* __restrict__ rot,
                                                      const float* __restrict__ trans,
                                                      float* __restrict__ concat)
{
    __shared__ float al[NH * NRES];    // 24 KB
    __shared__ float part[960];
    __shared__ float opt[NH * PV * 3];
    int i = blockIdx.x, t = threadIdx.x;
    for (int x = t; x < NH * NRES / 4; x += 1024)
        *(float4*)&al[x * 4] = *(const float4*)&A[(size_t)i * NH * NRES + x * 4];
    __syncthreads();

    if (t < 960) {
        int jh = (t >= 480) ? 1 : 0;
        int elem = t - jh * 480;
        float acc = 0.f;
        if (elem < 192) {
            int h = elem >> 4;
            const float* ah = al + h * NRES + jh * 256;
            const float* pv = proj + (size_t)(jh * 256) * PRJ + 384 + elem;
            for (int j = 0; j < 256; ++j) { acc = fmaf(ah[j], *pv, acc); pv += PRJ; }
        } else {
            int e = elem - 192;
            int h = e / 24;
            const float* ah = al + h * NRES + jh * 256;
            const float* pv = gv + (size_t)(jh * 256) * 288 + e;
            for (int j = 0; j < 256; ++j) { acc = fmaf(ah[j], *pv, acc); pv += 288; }
        }
        part[t] = acc;
    }
    __syncthreads();
    if (t < 480) {
        float v = part[t] + part[t + 480];
        if (t < 192) concat[(size_t)i * OUT_DIM + t] = v;
        else opt[t - 192] = v;
    }
    __syncthreads();
    if (t < 96) {
        int h = t >> 3, p = t & 7;
        float b0 = opt[h * 24 + p * 3 + 0] - trans[i * 3 + 0];
        float b1 = opt[h * 24 + p * 3 + 1] - trans[i * 3 + 1];
        float b2 = opt[h * 24 + p * 3 + 2] - trans[i * 3 + 2];
        const float* Ri = rot + i * 9;
        float l0 = Ri[0] * b0 + Ri[3] * b1 + Ri[6] * b2;
        float l1 = Ri[1] * b0 + Ri[4] * b1 + Ri[7] * b2;
        float l2 = Ri[2] * b0 + Ri[5] * b1 + Ri[8] * b2;
        float* c = concat + (size_t)i * OUT_DIM;
        c[192 + h * 24 + p * 3 + 0] = l0;
        c[192 + h * 24 + p * 3 + 1] = l1;
        c[192 + h * 24 + p * 3 + 2] = l2;
        c[480 + h * 8 + p] = sqrtf(l0 * l0 + l1 * l1 + l2 * l2 + 1e-8f);
    }
}

// ---------------------------------------------------------------------------
// LayerNorm over 384
// ---------------------------------------------------------------------------
__global__ void ln_kernel(const float* __restrict__ x, const float* __restrict__ g,
                          const float* __restrict__ b, float* __restrict__ y)
{
    int i = blockIdx.x, t = threadIdx.x;
    const float* xr = x + (size_t)i * CS;
    float a0 = xr[t], a1 = xr[t + 128], a2 = xr[t + 256];
    __shared__ float red[128];
    red[t] = a0 + a1 + a2;
    __syncthreads();
    for (int s = 64; s > 0; s >>= 1) { if (t < s) red[t] += red[t + s]; __syncthreads(); }
    float mean = red[0] * (1.f / CS);
    __syncthreads();
    float d0 = a0 - mean, d1 = a1 - mean, d2 = a2 - mean;
    red[t] = d0 * d0 + d1 * d1 + d2 * d2;
    __syncthreads();
    for (int s = 64; s > 0; s >>= 1) { if (t < s) red[t] += red[t + s]; __syncthreads(); }
    float rstd = rsqrtf(red[0] * (1.f / CS) + 1e-5f);
    float* yr = y + (size_t)i * CS;
    yr[t]       = d0 * rstd * g[t]       + b[t];
    yr[t + 128] = d1 * rstd * g[t + 128] + b[t + 128];
    yr[t + 256] = d2 * rstd * g[t + 256] + b[t + 256];
}

// ---------------------------------------------------------------------------
// Backbone: one block (128 thr) per residue; LDS reduce over 6 comps.
// ---------------------------------------------------------------------------
__global__ void backbone_kernel(const float* __restrict__ sfin, const float* __restrict__ Wbu,
                                const float* __restrict__ bbu, const float* __restrict__ rot,
                                const float* __restrict__ trans, float* __restrict__ rot_out,
                                float* __restrict__ trans_out)
{
    int i = blockIdx.x, t = threadIdx.x;
    float part[6] = {0.f, 0.f, 0.f, 0.f, 0.f, 0.f};
    for (int k = t; k < CS; k += 128) {
        float s = sfin[(size_t)i * CS + k];
        const float* wr = Wbu + k * 6;
#pragma unroll
        for (int c = 0; c < 6; ++c) part[c] = fmaf(s, wr[c], part[c]);
    }
    __shared__ float red[6][128];
#pragma unroll
    for (int c = 0; c < 6; ++c) red[c][t] = part[c];
    __syncthreads();
    for (int s = 64; s > 0; s >>= 1) {
        if (t < s) {
#pragma unroll
            for (int c = 0; c < 6; ++c) red[c][t] += red[c][t + s];
        }
        __syncthreads();
    }
    if (t == 0) {
        float u[6];
#pragma unroll
        for (int c = 0; c < 6; ++c) u[c] = red[c][0] + bbu[c];
        float a = 1.f, b = u[0], c2 = u[1], d = u[2];
        float inv = rsqrtf(a * a + b * b + c2 * c2 + d * d);
        a *= inv; b *= inv; c2 *= inv; d *= inv;
        float R[9] = { a*a + b*b - c2*c2 - d*d, 2.f*(b*c2 - a*d),        2.f*(b*d + a*c2),
                       2.f*(b*c2 + a*d),        a*a - b*b + c2*c2 - d*d, 2.f*(c2*d - a*b),
                       2.f*(b*d - a*c2),        2.f*(c2*d + a*b),        a*a - b*b - c2*c2 + d*d };
        const float* Ri = rot + i * 9;
        float Rn[9];
#pragma unroll
        for (int r = 0; r < 3; ++r)
#pragma unroll
            for (int cc = 0; cc < 3; ++cc) {
                float s2 = 0.f;
#pragma unroll
                for (int kk = 0; kk < 3; ++kk) s2 += Ri[r * 3 + kk] * R[kk * 3 + cc];
                Rn[r * 3 + cc] = s2;
            }
#pragma unroll
        for (int r = 0; r < 9; ++r) rot_out[i * 9 + r] = Rn[r];
        float t0 = u[3], t1 = u[4], t2 = u[5];
#pragma unroll
        for (int r = 0; r < 3; ++r)
            trans_out[i * 3 + r] = Ri[r * 3 + 0] * t0 + Ri[r * 3 + 1] * t1 + Ri[r * 3 + 2] * t2 + trans[i * 3 + r];
    }
}

// ---------------------------------------------------------------------------
// Loss
// ---------------------------------------------------------------------------
__global__ void loss_kernel(const float* __restrict__ rot_new, const float* __restrict__ trans_new,
                            const float* __restrict__ rot_truth, const float* __restrict__ trans_truth,
                            float* __restrict__ loss)
{
    int i = blockIdx.x;
    int t = threadIdx.x;
    __shared__ float red[256];
    float Rn[9], Rt[9];
#pragma unroll
    for (int r = 0; r < 9; ++r) { Rn[r] = rot_new[i * 9 + r]; Rt[r] = rot_truth[i * 9 + r]; }
    float ti0 = trans_new[i * 3 + 0], ti1 = trans_new[i * 3 + 1], ti2 = trans_new[i * 3 + 2];
    float tt0 = trans_truth[i * 3 + 0], tt1 = trans_truth[i * 3 + 1], tt2 = trans_truth[i * 3 + 2];
    float s = 0.f;
    for (int j = t; j < NRES; j += 256) {
        float db0 = trans_new[j * 3 + 0] - ti0;
        float db1 = trans_new[j * 3 + 1] - ti1;
        float db2 = trans_new[j * 3 + 2] - ti2;
        float dp0 = Rn[0] * db0 + Rn[3] * db1 + Rn[6] * db2;
        float dp1 = Rn[1] * db0 + Rn[4] * db1 + Rn[7] * db2;
        float dp2 = Rn[2] * db0 + Rn[5] * db1 + Rn[8] * db2;
        float eb0 = trans_truth[j * 3 + 0] - tt0;
        float eb1 = trans_truth[j * 3 + 1] - tt1;
        float eb2 = trans_truth[j * 3 + 2] - tt2;
        float dt0 = Rt[0] * eb0 + Rt[3] * eb1 + Rt[6] * eb2;
        float dt1 = Rt[1] * eb0 + Rt[4] * eb1 + Rt[7] * eb2;
        float dt2 = Rt[2] * eb0 + Rt[5] * eb1 + Rt[8] * eb2;
        float dx = dp0 - dt0, dy = dp1 - dt1, dz = dp2 - dt2;
        float dd = sqrtf(dx * dx + dy * dy + dz * dz + 1e-12f);
        s += fminf(dd, 10.f);
    }
    red[t] = s;
    __syncthreads();
    for (int k = 128; k > 0; k >>= 1) { if (t < k) red[t] += red[t + k]; __syncthreads(); }
    if (t == 0) atomicAdd(loss, red[0] * (1.f / (512.f * 512.f * 10.f)));
}

// ---------------------------------------------------------------------------
extern "C" void kernel_launch(void* const* d_in, const int* in_sizes, int n_in,
                              void* d_out, int out_size, void* d_ws, size_t ws_size,
                              hipStream_t stream)
{
    const float* single      = (const float*)d_in[0];
    const float* pair        = (const float*)d_in[1];
    const float* rot         = (const float*)d_in[2];
    const float* trans       = (const float*)d_in[3];
    const float* rot_truth   = (const float*)d_in[4];
    const float* trans_truth = (const float*)d_in[5];
    const float* Wq  = (const float*)d_in[6];
    const float* Wk  = (const float*)d_in[7];
    const float* Wv  = (const float*)d_in[8];
    const float* Wqp = (const float*)d_in[9];
    const float* Wkp = (const float*)d_in[10];
    const float* Wvp = (const float*)d_in[11];
    const float* Wb  = (const float*)d_in[12];
    const float* Wo  = (const float*)d_in[13];
    const float* bo  = (const float*)d_in[14];
    const float* gamma_raw = (const float*)d_in[15];
    const float* ln1_g = (const float*)d_in[16];
    const float* ln1_b = (const float*)d_in[17];
    const float* ln2_g = (const float*)d_in[18];
    const float* ln2_b = (const float*)d_in[19];
    const float* W1 = (const float*)d_in[20];
    const float* b1 = (const float*)d_in[21];
    const float* W2 = (const float*)d_in[22];
    const float* b2 = (const float*)d_in[23];
    const float* W3 = (const float*)d_in[24];
    const float* b3 = (const float*)d_in[25];
    const float* Wbu = (const float*)d_in[26];
    const float* bbu = (const float*)d_in[27];

    float* out = (float*)d_out;
    float* single_out = out;                   // 512*384
    float* rot_out    = out + 196608;          // 512*9
    float* trans_out  = out + 201216;          // 512*3
    float* loss_out   = out + 202752;          // 1

    float* ws = (float*)d_ws;
    float* proj   = ws;                         // 512*1152 = 589824
    float* gq     = proj   + 589824;            // 73728
    float* gv     = gq     + 73728;             // 147456
    float* sqq    = gv     + 147456;            // 6144
    float* kT     = sqq    + 6144;              // 98304
    float* gkT    = kT     + 98304;             // 73728
    float* sqkT   = gkT    + 73728;             // 6144
    float* Amat   = sqkT   + 6144;              // 3145728
    float* Bp     = Amat;                       // alias (used only before logits)
    float* concat = Amat   + 3145728;           // 1081344
    float* out1   = concat + 1081344;           // 196608
    float* sln    = out1   + 196608;            // 196608
    float* h1     = sln    + 196608;            // 196608
    float* h2     = h1     + 196608;            // 196608

    dim3 b256(256);

    // 1. pack projection weights; zero proj; fused projection GEMM (k-split 2)
    pack_proj_kernel<<<dim3((CS * PRJ + 255) / 256), b256, 0, stream>>>(Wq, Wk, Wv, Wqp, Wkp, Wvp, Bp);
    hipMemsetAsync(proj, 0, (size_t)NRES * PRJ * sizeof(float), stream);
    gemm_tiled<<<dim3(8, PRJ / 64, 2), b256, 0, stream>>>(single, Bp, nullptr, nullptr, proj,
                                                          NRES, CS, PRJ, 0, 192, 0);

    // 2. frames
    frames_kernel<<<dim3((NRES * NH + 255) / 256), b256, 0, stream>>>(proj, rot, trans,
                                                                      gq, gv, sqq, kT, gkT, sqkT);

    // 3. logits (one tile per block, grid 512x8) + softmax
    logits_mfma_kernel<<<dim3(NRES, 8), b256, 0, stream>>>(pair, proj, gq, kT, gkT, sqq, sqkT,
                                                           Wb, gamma_raw, Amat);
    softmax_kernel<<<dim3(NRES * NH), b256, 0, stream>>>(Amat);

    // 4. attention outputs (j-split in block)
    opair_kernel<<<dim3(NRES), dim3(768), 0, stream>>>(pair, Amat, concat);
    ov_opt_kernel<<<dim3(NRES), dim3(1024), 0, stream>>>(Amat, proj, gv, rot, trans, concat);

    // 5. ipa_out = concat @ Wo + bo + single  (k-split 4, atomic into pre-init)
    init_bias_kernel<<<dim3((NRES * CS + 255) / 256), b256, 0, stream>>>(bo, single, out1,
                                                                         NRES * CS, CS);
    gemm_tiled<<<dim3(8, CS / 64, 4), b256, 0, stream>>>(concat, Wo, nullptr, nullptr, out1,
                                                         NRES, OUT_DIM, CS, 0, 528, 0);

    // 6. LN1 + FF (k-split 4, relu folded into consumer A-load) + LN2
    ln_kernel<<<dim3(NRES), dim3(128), 0, stream>>>(out1, ln1_g, ln1_b, sln);
    init_bias_kernel<<<dim3((NRES * CS + 255) / 256), b256, 0, stream>>>(b1, nullptr, h1,
                                                                         NRES * CS, CS);
    init_bias_kernel<<<dim3((NRES * CS + 255) / 256), b256, 0, stream>>>(b2, nullptr, h2,
                                                                         NRES * CS, CS);
    gemm_tiled<<<dim3(8, CS / 64, 4), b256, 0, stream>>>(sln, W1, nullptr, nullptr, h1,
                                                         NRES, CS, CS, 0, 96, 0);
    gemm_tiled<<<dim3(8, CS / 64, 4), b256, 0, stream>>>(h1, W2, nullptr, nullptr, h2,
                                                         NRES, CS, CS, 0, 96, 1);
    init_bias_kernel<<<dim3((NRES * CS + 255) / 256), b256, 0, stream>>>(b3, sln, out1,
                                                                         NRES * CS, CS);
    gemm_tiled<<<dim3(8, CS / 64, 4), b256, 0, stream>>>(h2, W3, nullptr, nullptr, out1,
                                                         NRES, CS, CS, 0, 96, 1);
    ln_kernel<<<dim3(NRES), dim3(128), 0, stream>>>(out1, ln2_g, ln2_b, single_out);

    // 7. backbone + loss
    backbone_kernel<<<dim3(NRES), dim3(128), 0, stream>>>(single_out, Wbu, bbu, rot, trans,
                                                          rot_out, trans_out);
    hipMemsetAsync(loss_out, 0, sizeof(float), stream);
    loss_kernel<<<dim3(NRES), b256, 0, stream>>>(rot_out, trans_out, rot_truth, trans_truth, loss_out);
}